// Round 3
// baseline (282.651 us; speedup 1.0000x reference)
//
#include <hip/hip_runtime.h>
#include <cmath>

typedef _Float16 hf;
typedef hf hf8 __attribute__((ext_vector_type(8)));

constexpr int S = 160;
constexpr int BATCH = 4;
constexpr int TPB = 256;

// packed-fp16 path geometry: chunk = 8 t's
constexpr int KC8 = S / 8;          // 20 chunks per row
constexpr int LPR = 4;              // lanes per row
constexpr int CPL = KC8 / LPR;      // 5 chunks per lane
constexpr int RPP = TPB / LPR;      // 64 rows per block
constexpr int NZ = 3;               // z: rows {64,64,32}
constexpr int XROW = 3 * S;         // 480 hf per row: [A|B|C]

// fallback fp32 path geometry (r1 kernel, proven)
constexpr int FZSPLIT = 2;
constexpr int FROWS = S / FZSPLIT;  // 80
constexpr int FKC = S / 4;          // 40
constexpr int FLPR = 8;
constexpr int FCPL = FKC / FLPR;    // 5
constexpr int FRPP = TPB / FLPR;    // 32
constexpr int FPASSES = (FROWS + FRPP - 1) / FRPP;  // 3

__device__ __forceinline__ float sigmoidf_(float x) {
  return 1.0f / (1.0f + expf(-x));
}

// wf[b][h][t] = (mask[b][t][h] != 0 && t != h) ? 1 : 0   (byte)
__global__ void prep_wf(const int* __restrict__ mask, unsigned char* __restrict__ wf) {
  int i = blockIdx.x * blockDim.x + threadIdx.x;
  if (i >= BATCH * S * S) return;
  int t = i % S;
  int bh = i / S;
  int h = bh % S;
  int b = bh / S;
  wf[i] = (mask[(b * S + t) * S + h] != 0 && t != h) ? 1 : 0;
}

// Iter 1 (q1 == 0.5 analytic). Produces fully-masked fp16 rows packed as
// [A(160)|B(160)|C(160)] per (b,m,h) so consumers load 16B hf8 per array.
__global__ __launch_bounds__(TPB, 4) void mfvi_first(
    const float* __restrict__ s_edge,   // [b][m][h]
    const float* __restrict__ s_sib,    // [b][m][h][t]
    const float* __restrict__ s_cop,
    const float* __restrict__ s_grd,
    const int* __restrict__ mask,       // [b][x][y]
    const unsigned char* __restrict__ wf,  // [b][h][t]
    hf* __restrict__ X,                 // [b][m][h][3*S]
    float* __restrict__ q1_out,         // [b][h][m]
    float* __restrict__ q1t_out) {      // [b][m][h]
  const int m = blockIdx.x;
  const int b = blockIdx.y;
  const int z = blockIdx.z;
  const int tid = threadIdx.x;

  __shared__ float sef[RPP];
  __shared__ float pmf[RPP];

  const size_t bm = (size_t)b * S + m;
  const int h0 = z * RPP;
  const int nrows = (h0 + RPP <= S) ? RPP : (S - h0);

  if (tid < nrows) {
    sef[tid] = s_edge[bm * S + h0 + tid];
    pmf[tid] = (mask[bm * S + h0 + tid] != 0) ? 1.0f : 0.0f;
  }
  __syncthreads();

  const int r = tid >> 2;
  const int j = tid & 3;
  if (r >= nrows) return;
  const int h = h0 + r;

  const size_t rowf = (bm * S + h) * (size_t)S;
  const float4* SSr = (const float4*)(s_sib + rowf);
  const float4* CCr = (const float4*)(s_cop + rowf);
  const float4* GGr = (const float4*)(s_grd + rowf);
  const uint2* WFr = (const uint2*)(wf + ((size_t)b * S + h) * S);
  hf* Xr = X + (bm * S + h) * (size_t)XROW;

  const int msel8 = m >> 3;
  const unsigned mclr = ~(255u << ((m & 3) * 8));
  const float pm = pmf[r];

  float acc = 0.0f;
#pragma unroll
  for (int i = 0; i < CPL; ++i) {
    const int c = j + i * LPR;
    uint2 wu = WFr[c];
    float4 s0 = SSr[2 * c], s1 = SSr[2 * c + 1];
    float4 c0 = CCr[2 * c], c1 = CCr[2 * c + 1];
    float4 g0 = GGr[2 * c], g1 = GGr[2 * c + 1];
    if (c == msel8) { if (m & 4) wu.y &= mclr; else wu.x &= mclr; }
    const float w0 = (float)(wu.x & 255u) * pm;
    const float w1 = (float)((wu.x >> 8) & 255u) * pm;
    const float w2 = (float)((wu.x >> 16) & 255u) * pm;
    const float w3 = (float)(wu.x >> 24) * pm;
    const float w4 = (float)(wu.y & 255u) * pm;
    const float w5 = (float)((wu.y >> 8) & 255u) * pm;
    const float w6 = (float)((wu.y >> 16) & 255u) * pm;
    const float w7 = (float)(wu.y >> 24) * pm;

    const float a0 = w0 * s0.x, a1 = w1 * s0.y, a2 = w2 * s0.z, a3 = w3 * s0.w;
    const float a4 = w4 * s1.x, a5 = w5 * s1.y, a6 = w6 * s1.z, a7 = w7 * s1.w;
    const float b0 = w0 * c0.x, b1 = w1 * c0.y, b2 = w2 * c0.z, b3 = w3 * c0.w;
    const float b4 = w4 * c1.x, b5 = w5 * c1.y, b6 = w6 * c1.z, b7 = w7 * c1.w;
    const float e0 = w0 * g0.x, e1 = w1 * g0.y, e2 = w2 * g0.z, e3 = w3 * g0.w;
    const float e4 = w4 * g1.x, e5 = w5 * g1.y, e6 = w6 * g1.z, e7 = w7 * g1.w;

    acc += ((a0 + b0 + e0) + (a1 + b1 + e1)) + ((a2 + b2 + e2) + (a3 + b3 + e3)) +
           ((a4 + b4 + e4) + (a5 + b5 + e5)) + ((a6 + b6 + e6) + (a7 + b7 + e7));

    hf8 A = {(hf)a0, (hf)a1, (hf)a2, (hf)a3, (hf)a4, (hf)a5, (hf)a6, (hf)a7};
    hf8 B = {(hf)b0, (hf)b1, (hf)b2, (hf)b3, (hf)b4, (hf)b5, (hf)b6, (hf)b7};
    hf8 C = {(hf)e0, (hf)e1, (hf)e2, (hf)e3, (hf)e4, (hf)e5, (hf)e6, (hf)e7};
    *(hf8*)(Xr + 8 * c) = A;
    *(hf8*)(Xr + S + 8 * c) = B;
    *(hf8*)(Xr + 2 * S + 8 * c) = C;
  }
  acc += __shfl_xor(acc, 1);
  acc += __shfl_xor(acc, 2);
  if (j == 0) {
    const float qv = fmaf(0.5f, acc, sef[r]);   // pm folded into acc
    const float sg1 = sigmoidf_(qv);
    q1_out[((size_t)b * S + h) * S + m] = sg1;
    q1t_out[bm * S + h] = sg1;
  }
}

// Iters 2/3: triple-dot over packed fp16 rows. q1 stays fp32 (identical math).
template <bool LAST>
__global__ __launch_bounds__(TPB, 4) void mfvi_next(
    const float* __restrict__ s_edge,
    const hf* __restrict__ X,
    const float* __restrict__ q1_in,    // [b][h][m]
    const float* __restrict__ q1t_in,   // [b][m][h]
    float* __restrict__ q1_out, float* __restrict__ q1t_out,
    float* __restrict__ outp) {         // [b][m][h][2]
  const int m = blockIdx.x;
  const int b = blockIdx.y;
  const int z = blockIdx.z;
  const int tid = threadIdx.x;

  __shared__ __align__(16) float colm[S];   // q1[t][m]
  __shared__ __align__(16) float rowm[S];   // q1[m][t]
  __shared__ float sef[RPP];

  const size_t bm = (size_t)b * S + m;
  const int h0 = z * RPP;
  const int nrows = (h0 + RPP <= S) ? RPP : (S - h0);

  if (tid < S) {
    colm[tid] = q1t_in[bm * S + tid];
    rowm[tid] = q1_in[bm * S + tid];
    if (tid < nrows) sef[tid] = s_edge[bm * S + h0 + tid];
  }
  __syncthreads();

  const int r = tid >> 2;
  const int j = tid & 3;
  if (r >= nrows) return;
  const int h = h0 + r;

  const hf* Ar = X + (bm * S + h) * (size_t)XROW;
  const hf* Br = Ar + S;
  const hf* Cr = Ar + 2 * S;
  const float4* Qr = (const float4*)(q1_in + ((size_t)b * S + h) * (size_t)S);

  float acc = 0.0f;
#pragma unroll
  for (int i = 0; i < CPL; ++i) {
    const int c = j + i * LPR;
    hf8 A = *(const hf8*)(Ar + 8 * c);
    hf8 B = *(const hf8*)(Br + 8 * c);
    hf8 C = *(const hf8*)(Cr + 8 * c);
    float4 q0 = Qr[2 * c], q1v = Qr[2 * c + 1];
    float4 cm0 = ((const float4*)colm)[2 * c], cm1 = ((const float4*)colm)[2 * c + 1];
    float4 rm0 = ((const float4*)rowm)[2 * c], rm1 = ((const float4*)rowm)[2 * c + 1];
    acc = fmaf(q0.x, (float)A[0], fmaf(cm0.x, (float)B[0], fmaf(rm0.x, (float)C[0], acc)));
    acc = fmaf(q0.y, (float)A[1], fmaf(cm0.y, (float)B[1], fmaf(rm0.y, (float)C[1], acc)));
    acc = fmaf(q0.z, (float)A[2], fmaf(cm0.z, (float)B[2], fmaf(rm0.z, (float)C[2], acc)));
    acc = fmaf(q0.w, (float)A[3], fmaf(cm0.w, (float)B[3], fmaf(rm0.w, (float)C[3], acc)));
    acc = fmaf(q1v.x, (float)A[4], fmaf(cm1.x, (float)B[4], fmaf(rm1.x, (float)C[4], acc)));
    acc = fmaf(q1v.y, (float)A[5], fmaf(cm1.y, (float)B[5], fmaf(rm1.y, (float)C[5], acc)));
    acc = fmaf(q1v.z, (float)A[6], fmaf(cm1.z, (float)B[6], fmaf(rm1.z, (float)C[6], acc)));
    acc = fmaf(q1v.w, (float)A[7], fmaf(cm1.w, (float)B[7], fmaf(rm1.w, (float)C[7], acc)));
  }
  acc += __shfl_xor(acc, 1);
  acc += __shfl_xor(acc, 2);
  if (j == 0) {
    const float qv = sef[r] + acc;      // all masking folded into X
    if (!LAST) {
      const float sg1 = sigmoidf_(qv);
      q1_out[((size_t)b * S + h) * S + m] = sg1;
      q1t_out[bm * S + h] = sg1;
    } else {
      float2 o;
      o.x = sigmoidf_(-qv);
      o.y = sigmoidf_(qv);
      ((float2*)outp)[bm * S + h] = o;
    }
  }
}

// ---------------- fallback (proven fp32 path, r1 kernel) ----------------
template <bool FIRST, bool LAST>
__global__ __launch_bounds__(TPB, 4) void mfvi_iter(
    const float* __restrict__ s_edge, const float* __restrict__ s_sib,
    const float* __restrict__ s_cop, const float* __restrict__ s_grd,
    const int* __restrict__ mask, const unsigned char* __restrict__ wf,
    const float* __restrict__ q1_in, float* __restrict__ q1_out,
    float* __restrict__ outp) {
  const int m = blockIdx.x;
  const int b = blockIdx.y;
  const int z = blockIdx.z;
  const int tid = threadIdx.x;

  __shared__ __align__(16) float colm[S];
  __shared__ __align__(16) float rowm[S];
  __shared__ float sef[FROWS];
  __shared__ float pmf[FROWS];

  const float* G = q1_in + (size_t)b * S * S;
  const size_t bm = (size_t)b * S + m;
  const int h0 = z * FROWS;

  if (tid < S) {
    if (!FIRST) {
      colm[tid] = G[tid * S + m];
      rowm[tid] = G[m * S + tid];
    }
    if (tid < FROWS) {
      sef[tid] = s_edge[bm * S + h0 + tid];
      pmf[tid] = (mask[bm * S + h0 + tid] != 0) ? 1.0f : 0.0f;
    }
  }
  __syncthreads();

  const size_t blk = (bm * S + h0) * (size_t)S;
  const float4* SS = (const float4*)(s_sib + blk);
  const float4* CC = (const float4*)(s_cop + blk);
  const float4* GG = (const float4*)(s_grd + blk);
  const float4* QQ = (const float4*)(G + h0 * S);
  const unsigned* WF = (const unsigned*)(wf + ((size_t)b * S + h0) * S);
  const int msel = m >> 2;
  const unsigned mclr = ~(255u << ((m & 3) * 8));

  const int g = tid >> 3;
  const int j = tid & 7;

#pragma unroll
  for (int p = 0; p < FPASSES; ++p) {
    const int r = p * FRPP + g;
    if (r < FROWS) {
      const int rowbase = r * FKC;
      float acc = 0.0f;
#pragma unroll
      for (int i = 0; i < FCPL; ++i) {
        const int k = j + i * FLPR;
        const int c = rowbase + k;
        unsigned wu = WF[c];
        float4 s = SS[c];
        float4 cv = CC[c];
        float4 gv = GG[c];
        if (k == msel) wu &= mclr;
        float w0 = (float)(wu & 255u);
        float w1 = (float)((wu >> 8) & 255u);
        float w2 = (float)((wu >> 16) & 255u);
        float w3 = (float)(wu >> 24);
        if (FIRST) {
          float t0 = s.x + cv.x + gv.x;
          float t1 = s.y + cv.y + gv.y;
          float t2 = s.z + cv.z + gv.z;
          float t3 = s.w + cv.w + gv.w;
          acc = fmaf(w0, t0, fmaf(w1, t1, fmaf(w2, t2, fmaf(w3, t3, acc))));
        } else {
          float4 q = QQ[c];
          float4 cm = ((const float4*)colm)[k];
          float4 rm = ((const float4*)rowm)[k];
          float t0 = fmaf(q.x, s.x, fmaf(cm.x, cv.x, rm.x * gv.x));
          float t1 = fmaf(q.y, s.y, fmaf(cm.y, cv.y, rm.y * gv.y));
          float t2 = fmaf(q.z, s.z, fmaf(cm.z, cv.z, rm.z * gv.z));
          float t3 = fmaf(q.w, s.w, fmaf(cm.w, cv.w, rm.w * gv.w));
          acc = fmaf(w0, t0, fmaf(w1, t1, fmaf(w2, t2, fmaf(w3, t3, acc))));
        }
      }
      acc += __shfl_xor(acc, 1);
      acc += __shfl_xor(acc, 2);
      acc += __shfl_xor(acc, 4);
      if (j == 0) {
        const int h = h0 + r;
        const float qv = fmaf(pmf[r], FIRST ? 0.5f * acc : acc, sef[r]);
        if (!LAST) {
          q1_out[((size_t)b * S + h) * S + m] = sigmoidf_(qv);
        } else {
          float2 o;
          o.x = sigmoidf_(-qv);
          o.y = sigmoidf_(qv);
          ((float2*)outp)[bm * S + h] = o;
        }
      }
    }
  }
}

extern "C" void kernel_launch(void* const* d_in, const int* in_sizes, int n_in,
                              void* d_out, int out_size, void* d_ws, size_t ws_size,
                              hipStream_t stream) {
  const float* s_edge = (const float*)d_in[0];
  const float* s_sib = (const float*)d_in[1];
  const float* s_cop = (const float*)d_in[2];
  const float* s_grd = (const float*)d_in[3];
  const int* mask = (const int*)d_in[4];
  float* outp = (float*)d_out;

  const int qn = BATCH * S * S;                      // 102,400
  const size_t NS3 = (size_t)BATCH * S * S * S;      // 16,384,000 elements
  const size_t need = 3 * NS3 * sizeof(hf) + 4 * (size_t)qn * sizeof(float) + qn;

  if (ws_size >= need) {
    hf* X = (hf*)d_ws;                               // 3*NS3 hf, packed rows
    float* q1B = (float*)(X + 3 * NS3);
    float* q1Bt = q1B + qn;
    float* q1A = q1Bt + qn;
    float* q1At = q1A + qn;
    unsigned char* wf = (unsigned char*)(q1At + qn);

    prep_wf<<<(qn + 255) / 256, 256, 0, stream>>>(mask, wf);

    dim3 grid(S, BATCH, NZ);
    mfvi_first<<<grid, TPB, 0, stream>>>(
        s_edge, s_sib, s_cop, s_grd, mask, wf, X, q1B, q1Bt);
    mfvi_next<false><<<grid, TPB, 0, stream>>>(
        s_edge, X, q1B, q1Bt, q1A, q1At, nullptr);
    mfvi_next<true><<<grid, TPB, 0, stream>>>(
        s_edge, X, q1A, q1At, nullptr, nullptr, outp);
  } else {
    // fallback: proven fp32 path
    float* q1A = (float*)d_ws;
    float* q1B = q1A + qn;
    unsigned char* wf = (unsigned char*)(q1B + qn);

    prep_wf<<<(qn + 255) / 256, 256, 0, stream>>>(mask, wf);

    dim3 grid(S, BATCH, FZSPLIT);
    mfvi_iter<true, false><<<grid, TPB, 0, stream>>>(
        s_edge, s_sib, s_cop, s_grd, mask, wf, q1A, q1B, nullptr);
    mfvi_iter<false, false><<<grid, TPB, 0, stream>>>(
        s_edge, s_sib, s_cop, s_grd, mask, wf, q1B, q1A, nullptr);
    mfvi_iter<false, true><<<grid, TPB, 0, stream>>>(
        s_edge, s_sib, s_cop, s_grd, mask, wf, q1A, nullptr, outp);
  }
}

// Round 4
// 263.202 us; speedup vs baseline: 1.0739x; 1.0739x over previous
//
#include <hip/hip_runtime.h>
#include <cmath>

typedef _Float16 hf;
typedef hf hf4 __attribute__((ext_vector_type(4)));

constexpr int S = 160;
constexpr int BATCH = 4;
constexpr int TPB = 256;

// fp16 path geometry: chunk = 4 t's, 8 lanes/row, 32 rows/block, z in [0,5)
constexpr int KC = S / 4;           // 40 chunks per row
constexpr int LPR = 8;              // lanes per row
constexpr int CPL = KC / LPR;       // 5 chunks per lane
constexpr int RPB = TPB / LPR;      // 32 rows per block
constexpr int NZ = S / RPB;         // 5

// fallback fp32 path geometry (r1 kernel, proven)
constexpr int FZSPLIT = 2;
constexpr int FROWS = S / FZSPLIT;  // 80
constexpr int FKC = S / 4;          // 40
constexpr int FLPR = 8;
constexpr int FCPL = FKC / FLPR;    // 5
constexpr int FRPP = TPB / FLPR;    // 32
constexpr int FPASSES = (FROWS + FRPP - 1) / FRPP;  // 3

__device__ __forceinline__ float sigmoidf_(float x) {
  return 1.0f / (1.0f + expf(-x));
}

// wf[b][h][t] = (mask[b][t][h] != 0 && t != h) ? 1 : 0   (byte)
__global__ void prep_wf(const int* __restrict__ mask, unsigned char* __restrict__ wf) {
  int i = blockIdx.x * blockDim.x + threadIdx.x;
  if (i >= BATCH * S * S) return;
  int t = i % S;
  int bh = i / S;
  int h = bh % S;
  int b = bh / S;
  wf[i] = (mask[(b * S + t) * S + h] != 0 && t != h) ? 1 : 0;
}

// Iter 1 (q1 == 0.5 analytic) + produce fully-masked fp16 copies A/B/C.
// All 20 vmem loads per lane issued before any consumption (explicit MLP).
__global__ __launch_bounds__(TPB) void mfvi_first(
    const float* __restrict__ s_edge,   // [b][m][h]
    const float* __restrict__ s_sib,    // [b][m][h][t]
    const float* __restrict__ s_cop,
    const float* __restrict__ s_grd,
    const int* __restrict__ mask,       // [b][x][y]
    const unsigned char* __restrict__ wf,  // [b][h][t]
    hf* __restrict__ Aw, hf* __restrict__ Bw, hf* __restrict__ Cw,
    float* __restrict__ q1_out,         // [b][h][m]
    float* __restrict__ q1t_out) {      // [b][m][h]
  const int m = blockIdx.x;
  const int b = blockIdx.y;
  const int z = blockIdx.z;
  const int tid = threadIdx.x;

  __shared__ float sef[RPB];
  __shared__ float pmf[RPB];

  const size_t bm = (size_t)b * S + m;
  const int h0 = z * RPB;

  if (tid < RPB) {
    sef[tid] = s_edge[bm * S + h0 + tid];
    pmf[tid] = (mask[bm * S + h0 + tid] != 0) ? 1.0f : 0.0f;
  }
  __syncthreads();

  const int r = tid >> 3;
  const int j = tid & 7;
  const int h = h0 + r;

  const size_t rowf = (bm * S + h) * (size_t)S;
  const float4* SSr = (const float4*)(s_sib + rowf);
  const float4* CCr = (const float4*)(s_cop + rowf);
  const float4* GGr = (const float4*)(s_grd + rowf);
  const unsigned* WFr = (const unsigned*)(wf + ((size_t)b * S + h) * S);
  hf* Ar = Aw + rowf;
  hf* Br = Bw + rowf;
  hf* Cr = Cw + rowf;

  const int msel = m >> 2;
  const unsigned mclr = ~(255u << ((m & 3) * 8));
  const float pm = pmf[r];

  // ---- phase 1: issue ALL loads ----
  float4 sV[CPL], cV[CPL], gV[CPL];
  unsigned wV[CPL];
#pragma unroll
  for (int i = 0; i < CPL; ++i) {
    const int k = j + i * LPR;
    sV[i] = SSr[k];
    cV[i] = CCr[k];
    gV[i] = GGr[k];
    wV[i] = WFr[k];
  }

  // ---- phase 2: compute + store ----
  float accA = 0.0f, accB = 0.0f, accC = 0.0f;
#pragma unroll
  for (int i = 0; i < CPL; ++i) {
    const int k = j + i * LPR;
    unsigned wu = wV[i];
    if (k == msel) wu &= mclr;   // fold t != m
    const float w0 = (float)(wu & 255u) * pm;
    const float w1 = (float)((wu >> 8) & 255u) * pm;
    const float w2 = (float)((wu >> 16) & 255u) * pm;
    const float w3 = (float)(wu >> 24) * pm;
    const float a0 = w0 * sV[i].x, a1 = w1 * sV[i].y, a2 = w2 * sV[i].z, a3 = w3 * sV[i].w;
    const float b0 = w0 * cV[i].x, b1 = w1 * cV[i].y, b2 = w2 * cV[i].z, b3 = w3 * cV[i].w;
    const float e0 = w0 * gV[i].x, e1 = w1 * gV[i].y, e2 = w2 * gV[i].z, e3 = w3 * gV[i].w;
    accA += (a0 + a1) + (a2 + a3);
    accB += (b0 + b1) + (b2 + b3);
    accC += (e0 + e1) + (e2 + e3);
    hf4 A = {(hf)a0, (hf)a1, (hf)a2, (hf)a3};
    hf4 B = {(hf)b0, (hf)b1, (hf)b2, (hf)b3};
    hf4 C = {(hf)e0, (hf)e1, (hf)e2, (hf)e3};
    *(hf4*)(Ar + 4 * k) = A;
    *(hf4*)(Br + 4 * k) = B;
    *(hf4*)(Cr + 4 * k) = C;
  }
  float acc = accA + accB + accC;
  acc += __shfl_xor(acc, 1);
  acc += __shfl_xor(acc, 2);
  acc += __shfl_xor(acc, 4);
  if (j == 0) {
    const float qv = fmaf(0.5f, acc, sef[r]);   // pm folded into acc
    const float sg1 = sigmoidf_(qv);
    q1_out[((size_t)b * S + h) * S + m] = sg1;
    q1t_out[bm * S + h] = sg1;
  }
}

// Iters 2/3: triple-dot over pre-masked fp16 arrays, all loads batched first.
template <bool LAST>
__global__ __launch_bounds__(TPB) void mfvi_next(
    const float* __restrict__ s_edge,
    const hf* __restrict__ Aw, const hf* __restrict__ Bw, const hf* __restrict__ Cw,
    const float* __restrict__ q1_in,    // [b][h][m] layout [b][x][y]
    const float* __restrict__ q1t_in,   // [b][m][h]
    float* __restrict__ q1_out, float* __restrict__ q1t_out,
    float* __restrict__ outp) {         // [b][m][h][2]
  const int m = blockIdx.x;
  const int b = blockIdx.y;
  const int z = blockIdx.z;
  const int tid = threadIdx.x;

  __shared__ __align__(16) float colm[S];   // q1[t][m]
  __shared__ __align__(16) float rowm[S];   // q1[m][t]
  __shared__ float sef[RPB];

  const size_t bm = (size_t)b * S + m;
  const int h0 = z * RPB;

  if (tid < S) {
    colm[tid] = q1t_in[bm * S + tid];
    rowm[tid] = q1_in[bm * S + tid];     // q1[b][m][t] row is contiguous
    if (tid < RPB) sef[tid] = s_edge[bm * S + h0 + tid];
  }
  __syncthreads();

  const int r = tid >> 3;
  const int j = tid & 7;
  const int h = h0 + r;

  const size_t rowf = (bm * S + h) * (size_t)S;
  const hf* Ar = Aw + rowf;
  const hf* Br = Bw + rowf;
  const hf* Cr = Cw + rowf;
  const float4* Qr = (const float4*)(q1_in + ((size_t)b * S + h) * (size_t)S);

  // ---- phase 1: issue ALL loads ----
  hf4 aV[CPL], bV[CPL], cV[CPL];
  float4 qV[CPL];
#pragma unroll
  for (int i = 0; i < CPL; ++i) {
    const int k = j + i * LPR;
    aV[i] = *(const hf4*)(Ar + 4 * k);
    bV[i] = *(const hf4*)(Br + 4 * k);
    cV[i] = *(const hf4*)(Cr + 4 * k);
    qV[i] = Qr[k];
  }

  // ---- phase 2: consume (3 parallel acc chains) ----
  float accA = 0.0f, accB = 0.0f, accC = 0.0f;
#pragma unroll
  for (int i = 0; i < CPL; ++i) {
    const int k = j + i * LPR;
    const float4 cm = ((const float4*)colm)[k];
    const float4 rm = ((const float4*)rowm)[k];
    accA = fmaf(qV[i].x, (float)aV[i][0], accA);
    accA = fmaf(qV[i].y, (float)aV[i][1], accA);
    accA = fmaf(qV[i].z, (float)aV[i][2], accA);
    accA = fmaf(qV[i].w, (float)aV[i][3], accA);
    accB = fmaf(cm.x, (float)bV[i][0], accB);
    accB = fmaf(cm.y, (float)bV[i][1], accB);
    accB = fmaf(cm.z, (float)bV[i][2], accB);
    accB = fmaf(cm.w, (float)bV[i][3], accB);
    accC = fmaf(rm.x, (float)cV[i][0], accC);
    accC = fmaf(rm.y, (float)cV[i][1], accC);
    accC = fmaf(rm.z, (float)cV[i][2], accC);
    accC = fmaf(rm.w, (float)cV[i][3], accC);
  }
  float acc = accA + accB + accC;
  acc += __shfl_xor(acc, 1);
  acc += __shfl_xor(acc, 2);
  acc += __shfl_xor(acc, 4);
  if (j == 0) {
    const float qv = sef[r] + acc;      // all masking already folded
    if (!LAST) {
      const float sg1 = sigmoidf_(qv);
      q1_out[((size_t)b * S + h) * S + m] = sg1;
      q1t_out[bm * S + h] = sg1;
    } else {
      float2 o;
      o.x = sigmoidf_(-qv);
      o.y = sigmoidf_(qv);
      ((float2*)outp)[bm * S + h] = o;
    }
  }
}

// ---------------- fallback (proven fp32 path, r1 kernel) ----------------
template <bool FIRST, bool LAST>
__global__ __launch_bounds__(TPB, 4) void mfvi_iter(
    const float* __restrict__ s_edge, const float* __restrict__ s_sib,
    const float* __restrict__ s_cop, const float* __restrict__ s_grd,
    const int* __restrict__ mask, const unsigned char* __restrict__ wf,
    const float* __restrict__ q1_in, float* __restrict__ q1_out,
    float* __restrict__ outp) {
  const int m = blockIdx.x;
  const int b = blockIdx.y;
  const int z = blockIdx.z;
  const int tid = threadIdx.x;

  __shared__ __align__(16) float colm[S];
  __shared__ __align__(16) float rowm[S];
  __shared__ float sef[FROWS];
  __shared__ float pmf[FROWS];

  const float* G = q1_in + (size_t)b * S * S;
  const size_t bm = (size_t)b * S + m;
  const int h0 = z * FROWS;

  if (tid < S) {
    if (!FIRST) {
      colm[tid] = G[tid * S + m];
      rowm[tid] = G[m * S + tid];
    }
    if (tid < FROWS) {
      sef[tid] = s_edge[bm * S + h0 + tid];
      pmf[tid] = (mask[bm * S + h0 + tid] != 0) ? 1.0f : 0.0f;
    }
  }
  __syncthreads();

  const size_t blk = (bm * S + h0) * (size_t)S;
  const float4* SS = (const float4*)(s_sib + blk);
  const float4* CC = (const float4*)(s_cop + blk);
  const float4* GG = (const float4*)(s_grd + blk);
  const float4* QQ = (const float4*)(G + h0 * S);
  const unsigned* WF = (const unsigned*)(wf + ((size_t)b * S + h0) * S);
  const int msel = m >> 2;
  const unsigned mclr = ~(255u << ((m & 3) * 8));

  const int g = tid >> 3;
  const int j = tid & 7;

#pragma unroll
  for (int p = 0; p < FPASSES; ++p) {
    const int r = p * FRPP + g;
    if (r < FROWS) {
      const int rowbase = r * FKC;
      float acc = 0.0f;
#pragma unroll
      for (int i = 0; i < FCPL; ++i) {
        const int k = j + i * FLPR;
        const int c = rowbase + k;
        unsigned wu = WF[c];
        float4 s = SS[c];
        float4 cv = CC[c];
        float4 gv = GG[c];
        if (k == msel) wu &= mclr;
        float w0 = (float)(wu & 255u);
        float w1 = (float)((wu >> 8) & 255u);
        float w2 = (float)((wu >> 16) & 255u);
        float w3 = (float)(wu >> 24);
        if (FIRST) {
          float t0 = s.x + cv.x + gv.x;
          float t1 = s.y + cv.y + gv.y;
          float t2 = s.z + cv.z + gv.z;
          float t3 = s.w + cv.w + gv.w;
          acc = fmaf(w0, t0, fmaf(w1, t1, fmaf(w2, t2, fmaf(w3, t3, acc))));
        } else {
          float4 q = QQ[c];
          float4 cm = ((const float4*)colm)[k];
          float4 rm = ((const float4*)rowm)[k];
          float t0 = fmaf(q.x, s.x, fmaf(cm.x, cv.x, rm.x * gv.x));
          float t1 = fmaf(q.y, s.y, fmaf(cm.y, cv.y, rm.y * gv.y));
          float t2 = fmaf(q.z, s.z, fmaf(cm.z, cv.z, rm.z * gv.z));
          float t3 = fmaf(q.w, s.w, fmaf(cm.w, cv.w, rm.w * gv.w));
          acc = fmaf(w0, t0, fmaf(w1, t1, fmaf(w2, t2, fmaf(w3, t3, acc))));
        }
      }
      acc += __shfl_xor(acc, 1);
      acc += __shfl_xor(acc, 2);
      acc += __shfl_xor(acc, 4);
      if (j == 0) {
        const int h = h0 + r;
        const float qv = fmaf(pmf[r], FIRST ? 0.5f * acc : acc, sef[r]);
        if (!LAST) {
          q1_out[((size_t)b * S + h) * S + m] = sigmoidf_(qv);
        } else {
          float2 o;
          o.x = sigmoidf_(-qv);
          o.y = sigmoidf_(qv);
          ((float2*)outp)[bm * S + h] = o;
        }
      }
    }
  }
}

extern "C" void kernel_launch(void* const* d_in, const int* in_sizes, int n_in,
                              void* d_out, int out_size, void* d_ws, size_t ws_size,
                              hipStream_t stream) {
  const float* s_edge = (const float*)d_in[0];
  const float* s_sib = (const float*)d_in[1];
  const float* s_cop = (const float*)d_in[2];
  const float* s_grd = (const float*)d_in[3];
  const int* mask = (const int*)d_in[4];
  float* outp = (float*)d_out;

  const int qn = BATCH * S * S;                      // 102,400
  const size_t NS3 = (size_t)BATCH * S * S * S;      // 16,384,000 elements
  const size_t need = 3 * NS3 * sizeof(hf) + 4 * (size_t)qn * sizeof(float) + qn;

  if (ws_size >= need) {
    hf* Aw = (hf*)d_ws;
    hf* Bw = Aw + NS3;
    hf* Cw = Bw + NS3;
    float* q1B = (float*)(Cw + NS3);
    float* q1Bt = q1B + qn;
    float* q1A = q1Bt + qn;
    float* q1At = q1A + qn;
    unsigned char* wf = (unsigned char*)(q1At + qn);

    prep_wf<<<(qn + 255) / 256, 256, 0, stream>>>(mask, wf);

    dim3 grid(S, BATCH, NZ);
    mfvi_first<<<grid, TPB, 0, stream>>>(
        s_edge, s_sib, s_cop, s_grd, mask, wf, Aw, Bw, Cw, q1B, q1Bt);
    mfvi_next<false><<<grid, TPB, 0, stream>>>(
        s_edge, Aw, Bw, Cw, q1B, q1Bt, q1A, q1At, nullptr);
    mfvi_next<true><<<grid, TPB, 0, stream>>>(
        s_edge, Aw, Bw, Cw, q1A, q1At, nullptr, nullptr, outp);
  } else {
    // fallback: proven fp32 path
    float* q1A = (float*)d_ws;
    float* q1B = q1A + qn;
    unsigned char* wf = (unsigned char*)(q1B + qn);

    prep_wf<<<(qn + 255) / 256, 256, 0, stream>>>(mask, wf);

    dim3 grid(S, BATCH, FZSPLIT);
    mfvi_iter<true, false><<<grid, TPB, 0, stream>>>(
        s_edge, s_sib, s_cop, s_grd, mask, wf, q1A, q1B, nullptr);
    mfvi_iter<false, false><<<grid, TPB, 0, stream>>>(
        s_edge, s_sib, s_cop, s_grd, mask, wf, q1B, q1A, nullptr);
    mfvi_iter<false, true><<<grid, TPB, 0, stream>>>(
        s_edge, s_sib, s_cop, s_grd, mask, wf, q1A, nullptr, outp);
  }
}